// Round 16
// baseline (377.075 us; speedup 1.0000x reference)
//
#include <hip/hip_runtime.h>

#define N_PIX 16384
#define CC 192
#define C3 576
#define KTOT 192
#define NCH 32
#define CHUNK 512

typedef __bf16 bf16_t;
typedef bf16_t bf16x4 __attribute__((ext_vector_type(4)));
typedef bf16_t bf16x8 __attribute__((ext_vector_type(8)));
typedef float f32x4 __attribute__((ext_vector_type(4)));

struct WPtrs { const float* p[4]; };
struct GArgs { const float* W[16]; long xoff[16]; long yoff[16]; int sel[16]; };

// ---------------- MFMA GEMM: Y[m][n] = sum_k W[m][k] * X[k][n], K=192 --------
// 64m x 128n tile. W staged to LDS once (full K). X DOUBLE-BUFFERED in LDS,
// ONE barrier/iter, and no VMEM op in flight across any barrier: rounds 8-14
// all kept the t+1 prefetch in flight across __syncthreads(), and HIP emits
// s_waitcnt vmcnt(0) before s_barrier — the prefetch was drained at the
// barrier every time (the m97 ~20% stall, here dominant). Now loads issue at
// iter top and are consumed by writeX AFTER the MFMAs, within the same
// inter-barrier segment. X writes use a kb^(n&7) XOR column swizzle: r14's
// straight layout was 8-way write-conflicted (17.7M). A/B frags share
// k-bijection phi(gi,e)=16*(e>>2)+4*gi+(e&3); C/D map col=lane&15,
// row=4*(lane>>4)+reg [m89-verified].
template <typename XT, typename YT>
__global__ __launch_bounds__(256) void gemm_k192(GArgs ga,
    const XT* __restrict__ X0, const XT* __restrict__ X1,
    YT* __restrict__ Y, long /*unused*/)
{
    __shared__ __align__(16) bf16_t Wl[64][200];     // 64m x 192k (+8) 25.6KB
    __shared__ __align__(16) bf16_t Xl[2][128][36];  // 2 x 9KB, XOR-swizzled k
    const int bt = blockIdx.z;
    const float* __restrict__ W = ga.W[bt];
    const XT* __restrict__ Xb = (ga.sel[bt] ? X1 : X0) + ga.xoff[bt];
    YT* __restrict__ Yb = Y + ga.yoff[bt];
    const int m0 = blockIdx.y * 64, n0 = blockIdx.x * 128;
    const int tid = threadIdx.x;
    const int w = tid >> 6;
    const int gi = (tid >> 4) & 3;
    const int li = tid & 15;
    const int kb4 = tid >> 5;       // 0..7 : owns k rows 4*kb4..+3
    const int nb4 = tid & 31;       // 0..31: owns n cols 4*nb4..+3
    const int wcol = 4 * (kb4 ^ (nb4 & 7));   // swizzled k-column for writes

    f32x4 xf[4];                    // f32 staging (4 k-rows x 4 n)
    bf16x4 xh[4];                   // bf16 staging

    auto loadX = [&](int t) {       // n-contiguous vector loads
        const XT* p = Xb + (long)(32 * t + 4 * kb4) * N_PIX + n0 + 4 * nb4;
        #pragma unroll
        for (int j = 0; j < 4; ++j) {
            if constexpr (sizeof(XT) == 4)
                xf[j] = *(const f32x4*)(p + (long)j * N_PIX);
            else
                xh[j] = *(const bf16x4*)(p + (long)j * N_PIX);
        }
    };
    auto writeX = [&](int buf) {    // 4x4 register transpose -> n-major LDS
        #pragma unroll
        for (int i = 0; i < 4; ++i) {
            bf16x4 v;
            if constexpr (sizeof(XT) == 4)
                v = bf16x4{ (bf16_t)xf[0][i], (bf16_t)xf[1][i],
                            (bf16_t)xf[2][i], (bf16_t)xf[3][i] };
            else
                v = bf16x4{ xh[0][i], xh[1][i], xh[2][i], xh[3][i] };
            *(bf16x4*)&Xl[buf][4 * nb4 + i][wcol] = v;
        }
    };

    loadX(0);
    // stage all of W: 4 threads/row, each 48 k = 6 bf16x8 segments
    {
        const int wr = tid >> 2, wkb = (tid & 3) * 48;
        #pragma unroll
        for (int j = 0; j < 6; ++j) {
            const float* wp0 = W + (long)(m0 + wr) * KTOT + wkb + 8 * j;
            float4 a = *(const float4*)(wp0);
            float4 b = *(const float4*)(wp0 + 4);
            bf16x8 v = { (bf16_t)a.x, (bf16_t)a.y, (bf16_t)a.z, (bf16_t)a.w,
                         (bf16_t)b.x, (bf16_t)b.y, (bf16_t)b.z, (bf16_t)b.w };
            *(bf16x8*)&Wl[wr][wkb + 8 * j] = v;
        }
    }
    writeX(0);                      // vmcnt waits for tile 0 here
    __syncthreads();                // Wl + Xl[0] ready; nothing in flight

    f32x4 acc[4][2];
    #pragma unroll
    for (int i = 0; i < 4; ++i)
        #pragma unroll
        for (int j = 0; j < 2; ++j) acc[i][j] = 0.f;

    #pragma unroll
    for (int t = 0; t < 6; ++t) {
        const int cur = t & 1;                   // static after full unroll
        if (t < 5) loadX(t + 1);                 // issue; consumed below, no
                                                 // barrier in between
        const int kb = 32 * t;
        bf16x8 af[4], bfr[2];
        #pragma unroll
        for (int mi = 0; mi < 4; ++mi) {
            bf16x4 lo = *(const bf16x4*)&Wl[16 * mi + li][kb + 4 * gi];
            bf16x4 hi = *(const bf16x4*)&Wl[16 * mi + li][kb + 16 + 4 * gi];
            af[mi] = __builtin_shufflevector(lo, hi, 0, 1, 2, 3, 4, 5, 6, 7);
        }
        #pragma unroll
        for (int ni = 0; ni < 2; ++ni) {
            const int n = 32 * w + 16 * ni + li;
            const int swz = (n >> 2) & 7;
            bf16x4 lo = *(const bf16x4*)&Xl[cur][n][4 * (gi ^ swz)];
            bf16x4 hi = *(const bf16x4*)&Xl[cur][n][4 * ((gi + 4) ^ swz)];
            bfr[ni] = __builtin_shufflevector(lo, hi, 0, 1, 2, 3, 4, 5, 6, 7);
        }
        #pragma unroll
        for (int mi = 0; mi < 4; ++mi)
            #pragma unroll
            for (int ni = 0; ni < 2; ++ni)
                acc[mi][ni] = __builtin_amdgcn_mfma_f32_16x16x32_bf16(
                    af[mi], bfr[ni], acc[mi][ni], 0, 0, 0);
        if (t < 5) writeX(cur ^ 1);              // vmcnt satisfied after MFMAs
        __syncthreads();                         // drain already satisfied
    }
    #pragma unroll
    for (int mi = 0; mi < 4; ++mi)
        #pragma unroll
        for (int ni = 0; ni < 2; ++ni) {
            const int n = n0 + 32 * w + 16 * ni + li;
            #pragma unroll
            for (int r = 0; r < 4; ++r) {
                const int m = m0 + 16 * mi + 4 * gi + r;
                Yb[(long)m * N_PIX + n] = (YT)acc[mi][ni][r];
            }
        }
}

// ---------------- depthwise 3x3 + fused row L2-norm ----------------
__global__ __launch_bounds__(256) void dwconv3b(const bf16_t* __restrict__ Yin,
    const float* __restrict__ wdw, bf16_t* __restrict__ Z,
    float* __restrict__ invn)
{
    const int ch = blockIdx.x, sb = blockIdx.y;
    const int tid = threadIdx.x;
    const int x0 = (tid & 15) << 3;
    const int y0 = (tid >> 4) << 3;
    const bf16_t* __restrict__ inp = Yin + (long)(sb * C3 + ch) * N_PIX;
    bf16_t* __restrict__ outp = Z + (long)(sb * C3 + ch) * N_PIX;
    const float* wch = wdw + ch * 9;
    const float w00 = wch[0], w01 = wch[1], w02 = wch[2];
    const float w10 = wch[3], w11 = wch[4], w12 = wch[5];
    const float w20 = wch[6], w21 = wch[7], w22 = wch[8];
    const bool hasL = (x0 > 0), hasR = (x0 < 120);
    float A[10], B[10], Cr[10];
    auto loadrow = [&](int yy, float* r) {
        if (yy < 0 || yy > 127) {
            #pragma unroll
            for (int i = 0; i < 10; ++i) r[i] = 0.f;
            return;
        }
        const bf16_t* p = inp + (yy << 7);
        bf16x8 v = *(const bf16x8*)(p + x0);
        #pragma unroll
        for (int j = 0; j < 8; ++j) r[1 + j] = (float)v[j];
        r[0] = hasL ? (float)p[x0 - 1] : 0.f;
        r[9] = hasR ? (float)p[x0 + 8] : 0.f;
    };
    loadrow(y0 - 1, A);
    loadrow(y0,     B);
    float ss = 0.f;
    #pragma unroll
    for (int r = 0; r < 8; ++r) {
        loadrow(y0 + r + 1, Cr);
        bf16x8 ov;
        #pragma unroll
        for (int i = 0; i < 8; ++i) {
            float s;
            s = fmaf(w00, A[i],  fmaf(w01, A[i + 1],  w02 * A[i + 2]));
            s = fmaf(w10, B[i],  fmaf(w11, B[i + 1],  fmaf(w12, B[i + 2], s)));
            s = fmaf(w20, Cr[i], fmaf(w21, Cr[i + 1], fmaf(w22, Cr[i + 2], s)));
            ov[i] = (bf16_t)s;
            const float vb = (float)ov[i];
            ss = fmaf(vb, vb, ss);
        }
        *(bf16x8*)(outp + ((y0 + r) << 7) + x0) = ov;
        #pragma unroll
        for (int i = 0; i < 10; ++i) { A[i] = B[i]; B[i] = Cr[i]; }
    }
    if (ch < 384) {
        #pragma unroll
        for (int off = 32; off > 0; off >>= 1) ss += __shfl_down(ss, off);
        __shared__ float red[4];
        if ((tid & 63) == 0) red[tid >> 6] = ss;
        __syncthreads();
        if (tid == 0) {
            const float t = red[0] + red[1] + red[2] + red[3];
            const int row = (sb >> 2) * 1536 + (sb & 3) * 384 + ch;
            invn[row] = 1.f / fmaxf(sqrtf(t), 1e-12f);
        }
    }
}

// ---------------- MFMA score partials: all 4 combos share one LDS stage ------
__global__ __launch_bounds__(256) void scores_mfma(const bf16_t* __restrict__ Z,
                                                   float* __restrict__ part)
{
    const int c = blockIdx.x;
    const int bh = blockIdx.y;
    const int b = bh >> 2, h = bh & 3;
    __shared__ __align__(16) bf16_t T[4][48][72];   // qe, qd, ke, kd
    const int tid = threadIdx.x;
    const int m = tid >> 6;
    const int gi = (tid >> 4) & 3, li = tid & 15;
    const int qs = (m == 1 || m == 3) ? 1 : 0;
    const int ks = (m == 1 || m == 2) ? 1 : 0;
    f32x4 acc[3][3];
    #pragma unroll
    for (int i = 0; i < 3; ++i)
        #pragma unroll
        for (int j = 0; j < 3; ++j) acc[i][j] = 0.f;

    const int nbase = c * CHUNK;
    for (int k0 = 0; k0 < CHUNK; k0 += 64) {
        __syncthreads();
        for (int l = tid; l < 1536; l += 256) {
            const int t = l / 384;
            const int rem = l - t * 384;
            const int r = rem >> 3, s = rem & 7;
            const int sidx = (t < 2) ? t : (t - 2);
            const int qk = (t < 2) ? 0 : 1;
            const bf16_t* gp = Z + ((long)((sidx * 4 + b) * C3 + qk * 192 + h * 48 + r)) * N_PIX
                                 + nbase + k0 + s * 8;
            *(bf16x8*)&T[t][r][s * 8] = *(const bf16x8*)gp;
        }
        __syncthreads();
        #pragma unroll
        for (int k2 = 0; k2 < 64; k2 += 32) {
            bf16x8 af[3], bfr[3];
            #pragma unroll
            for (int i = 0; i < 3; ++i) {
                bf16x4 lo = *(const bf16x4*)&T[qs][16 * i + li][k2 + 4 * gi];
                bf16x4 hi = *(const bf16x4*)&T[qs][16 * i + li][k2 + 16 + 4 * gi];
                af[i] = __builtin_shufflevector(lo, hi, 0, 1, 2, 3, 4, 5, 6, 7);
            }
            #pragma unroll
            for (int j = 0; j < 3; ++j) {
                bf16x4 lo = *(const bf16x4*)&T[2 + ks][16 * j + li][k2 + 4 * gi];
                bf16x4 hi = *(const bf16x4*)&T[2 + ks][16 * j + li][k2 + 16 + 4 * gi];
                bfr[j] = __builtin_shufflevector(lo, hi, 0, 1, 2, 3, 4, 5, 6, 7);
            }
            #pragma unroll
            for (int i = 0; i < 3; ++i)
                #pragma unroll
                for (int j = 0; j < 3; ++j)
                    acc[i][j] = __builtin_amdgcn_mfma_f32_16x16x32_bf16(
                        af[i], bfr[j], acc[i][j], 0, 0, 0);
        }
    }
    const long base = ((long)(m * 16 + bh) * NCH + c) * 2304;
    #pragma unroll
    for (int i = 0; i < 3; ++i)
        #pragma unroll
        for (int j = 0; j < 3; ++j) {
            const int e = 16 * j + li;
            #pragma unroll
            for (int r = 0; r < 4; ++r) {
                const int d = 16 * i + 4 * gi + r;
                part[base + d * 48 + e] = acc[i][j][r];
            }
        }
}

// ---------------- reduce partials, scale by norms+temperature, softmax -------
__global__ __launch_bounds__(256) void reduce_softmax(const float* __restrict__ part,
    const float* __restrict__ invn, const float* __restrict__ temp,
    float* __restrict__ attn)
{
    const int mbh = blockIdx.x;                 // 64
    const int m = mbh >> 4, b = (mbh >> 2) & 3, h = mbh & 3;
    const int qs = (m == 1 || m == 3) ? 1 : 0;
    const int ks = (m == 1 || m == 2) ? 1 : 0;
    __shared__ float sm[48][48];
    const int tid = threadIdx.x;
    const long pbase = (long)mbh * NCH * 2304;
    const float T = temp[h];
    for (int idx = tid; idx < 2304; idx += 256) {
        float v = 0.f;
        #pragma unroll 8
        for (int c = 0; c < NCH; ++c) v += part[pbase + c * 2304 + idx];
        const int d = idx / 48, e = idx % 48;
        const float iq = invn[(qs * 4 + b) * 384 + h * 48 + d];
        const float ik = invn[(ks * 4 + b) * 384 + 192 + h * 48 + e];
        sm[d][e] = v * iq * ik * T;
    }
    __syncthreads();
    if (tid < 48) {
        float mx = -1e30f;
        #pragma unroll
        for (int e = 0; e < 48; ++e) mx = fmaxf(mx, sm[tid][e]);
        float sum = 0.f;
        #pragma unroll
        for (int e = 0; e < 48; ++e) {
            const float v = __expf(sm[tid][e] - mx);
            sm[tid][e] = v;
            sum += v;
        }
        const float inv = 1.f / sum;
        const long abase = (long)mbh * 2304 + (long)tid * 48;
        #pragma unroll
        for (int e = 0; e < 48; ++e) attn[abase + e] = sm[tid][e] * inv;
    }
}

// ---------------- fold attn into projection: M[m][b][o][h*48+e] --------------
// m==3 (inter_de): einsum '...de,bhen->bhdn' SUMS the ellipsis dims.
__global__ __launch_bounds__(256) void make_M(const float* __restrict__ attn,
                                              WPtrs wp, float* __restrict__ M)
{
    const int h = blockIdx.x & 3;
    const int b = (blockIdx.x >> 2) & 3;
    const int m = blockIdx.x >> 4;              // grid 64
    __shared__ float A[48][48];
    const int tid = threadIdx.x;
    if (m == 3) {
        for (int l = tid; l < 2304; l += 256) {
            float s = 0.f;
            #pragma unroll
            for (int bb = 0; bb < 16; ++bb)
                s += attn[(long)(48 + bb) * 2304 + l];
            A[l / 48][l % 48] = s;
        }
    } else {
        const long ab = (long)(m * 16 + b * 4 + h) * 2304;
        for (int l = tid; l < 2304; l += 256)
            A[l / 48][l % 48] = attn[ab + l];
    }
    __syncthreads();
    const float* W = wp.p[m];
    float* Mo = M + (long)(m * 4 + b) * 192 * 192;
    for (int o = tid >> 4; o < 192; o += 16) {
        const float* wrow = W + (long)o * 192 + h * 48;
        for (int e2 = tid & 15; e2 < 48; e2 += 16) {
            float s = 0.f;
            #pragma unroll
            for (int d = 0; d < 48; ++d) s = fmaf(wrow[d], A[d][e2], s);
            Mo[(long)o * 192 + h * 48 + e2] = s;
        }
    }
}

extern "C" void kernel_launch(void* const* d_in, const int* in_sizes, int n_in,
                              void* d_out, int out_size, void* d_ws, size_t ws_size,
                              hipStream_t stream)
{
    const float* e     = (const float*)d_in[0];
    const float* d     = (const float*)d_in[1];
    const float* temp  = (const float*)d_in[2];
    const float* w_qkv = (const float*)d_in[3];
    const float* w_dw  = (const float*)d_in[4];
    const float* w_p1  = (const float*)d_in[5];
    const float* w_p2  = (const float*)d_in[6];
    const float* w_p3  = (const float*)d_in[7];
    const float* w_p4  = (const float*)d_in[8];
    float* out = (float*)d_out;
    float* ws  = (float*)d_ws;

    // workspace layout (float units)
    bf16_t* zraw = (bf16_t*)ws;                // 75,497,472 bf16 (qkv raw)
    bf16_t* zb   = (bf16_t*)(ws + 37748736L);  // 75,497,472 bf16
    float* attn  = ws + 75497472L;             // 147,456
    float* invn  = ws + 75644928L;             // 3,072
    // part & M reuse the zraw region once it's dead (after dwconv3b)
    float* part  = ws;                         // 4,718,592 f32
    float* Mmat  = ws + 8388608L;              // 589,824 f32

    const long sXin = (long)CC * N_PIX;
    const long sQKV = (long)C3 * N_PIX;

    // 1) pointwise qkv GEMM, bf16 output — ONE launch for e (bt 0..3, X0) and
    //    d (bt 4..7, X1)
    GArgs gq{};
    for (int bt = 0; bt < 8; ++bt) {
        gq.W[bt] = w_qkv;
        gq.xoff[bt] = (long)(bt & 3) * sXin;
        gq.yoff[bt] = (long)bt * sQKV;
        gq.sel[bt] = bt >> 2;
    }
    gemm_k192<float, bf16_t><<<dim3(128, 9, 8), 256, 0, stream>>>(gq, e, d, zraw, 0);
    // 2) depthwise 3x3 (bf16 -> bf16) + fused q/k row norms
    dwconv3b<<<dim3(C3, 8), 256, 0, stream>>>(zraw, w_dw, zb, invn);
    // 3) MFMA score partials, 4 combos fused (part reuses dead zraw region)
    scores_mfma<<<dim3(NCH, 16), 256, 0, stream>>>(zb, part);
    // 4) reduce + scale + softmax
    reduce_softmax<<<dim3(64), 256, 0, stream>>>(part, invn, temp, attn);
    // 5) fold attn into projection matrices
    WPtrs wpj; wpj.p[0] = w_p1; wpj.p[1] = w_p2; wpj.p[2] = w_p3; wpj.p[3] = w_p4;
    make_M<<<dim3(64), 256, 0, stream>>>(attn, wpj, Mmat);
    // 6) fused (proj ∘ attn) @ V into d_out; batch order interleaved so
    //    consecutive z share the same V panel (L2 locality): (m0,m3) use v_e,
    //    (m1,m2) use v_d.
    GArgs gm{};
    const int morder[16] = {0,3,0,3,0,3,0,3, 1,2,1,2,1,2,1,2};
    const int border[16] = {0,0,1,1,2,2,3,3, 0,0,1,1,2,2,3,3};
    for (int z = 0; z < 16; ++z) {
        const int m = morder[z], b = border[z];
        const int ks = (m == 1 || m == 2) ? 1 : 0;
        gm.W[z] = Mmat + (long)(m * 4 + b) * 192 * 192;
        gm.xoff[z] = ((long)((ks * 4 + b) * C3 + 384)) * N_PIX;
        gm.yoff[z] = (long)(m * 4 + b) * sXin;
        gm.sel[z] = 0;
    }
    gemm_k192<bf16_t, float><<<dim3(128, 3, 16), 256, 0, stream>>>(gm, zb, zb, out, 0);
}

// Round 17
// 334.154 us; speedup vs baseline: 1.1284x; 1.1284x over previous
//
#include <hip/hip_runtime.h>

#define N_PIX 16384
#define CC 192
#define C3 576
#define KTOT 192
#define NCH 32
#define CHUNK 512

typedef __bf16 bf16_t;
typedef bf16_t bf16x4 __attribute__((ext_vector_type(4)));
typedef bf16_t bf16x8 __attribute__((ext_vector_type(8)));
typedef float f32x4 __attribute__((ext_vector_type(4)));

struct WPtrs { const float* p[4]; };
struct GArgs { const float* W[16]; long xoff[16]; long yoff[16]; int sel[16]; };

// ------- m-outer MFMA GEMM: per block, X(128n x 192k) lives in REGISTERS ----
// Rounds 7-16 were invariant at 124-137us: grid.y=9 re-read the X panel once
// per m-tile => 906MB through L3 (panels >> 4MB/XCD L2) — a traffic constant
// no schedule change touched. Now each block loads its B-fragments ONCE
// (24 VGPR as 12x bf16x8) and loops all output tiles (qkv: 9; proj: 2x3),
// streaming only W (L2-resident, reg-prefetched under MFMAs). No X in LDS.
// k-bijection phi'(gi,e)=8*gi+e shared by A and B (any shared bijection is
// valid — sum over k is permutation-invariant; 12 rounds validated the
// technique). C/D map col=lane&15, row=4*(lane>>4)+reg [m89-verified].
template <typename XT, typename YT, int NC, int NMT>
__global__ __launch_bounds__(256) void gemm_mloop(GArgs ga,
    const XT* __restrict__ X0, const XT* __restrict__ X1, YT* __restrict__ Y)
{
    __shared__ __align__(16) bf16_t Wl[64][200];   // 64m x 192k (+8) 25.6KB
    const int z = blockIdx.y;
    const XT* __restrict__ Xb = (ga.sel[z] ? X1 : X0) + ga.xoff[z];
    const int n0 = blockIdx.x * 128;
    const int tid = threadIdx.x;
    const int w = tid >> 6;
    const int gi = (tid >> 4) & 3;
    const int li = tid & 15;

    // ---- B-fragments for the whole block, loaded once. elem e -> k=32t+8gi+e
    bf16x8 xfrag[6][2];
    #pragma unroll
    for (int t = 0; t < 6; ++t)
        #pragma unroll
        for (int ni = 0; ni < 2; ++ni) {
            const XT* xp = Xb + (long)(32 * t + 8 * gi) * N_PIX
                              + n0 + 32 * w + 16 * ni + li;
            bf16x8 v;
            #pragma unroll
            for (int e = 0; e < 8; ++e) v[e] = (bf16_t)xp[(long)e * N_PIX];
            xfrag[t][ni] = v;
        }

    // ---- W staging: thread owns row wr, 48 k starting at wkb
    const int wr = tid >> 2, wkb = (tid & 3) * 48;
    float wreg[48];
    auto loadW = [&](int it) {
        const int c = it / NMT, j = it % NMT;
        const float* base = ga.W[z * NC + c] + (long)(64 * j + wr) * KTOT + wkb;
        #pragma unroll
        for (int q = 0; q < 12; ++q) {
            float4 a = *(const float4*)(base + 4 * q);
            wreg[4 * q + 0] = a.x; wreg[4 * q + 1] = a.y;
            wreg[4 * q + 2] = a.z; wreg[4 * q + 3] = a.w;
        }
    };
    auto writeW = [&]() {
        #pragma unroll
        for (int s = 0; s < 6; ++s) {
            bf16x8 v = { (bf16_t)wreg[8 * s + 0], (bf16_t)wreg[8 * s + 1],
                         (bf16_t)wreg[8 * s + 2], (bf16_t)wreg[8 * s + 3],
                         (bf16_t)wreg[8 * s + 4], (bf16_t)wreg[8 * s + 5],
                         (bf16_t)wreg[8 * s + 6], (bf16_t)wreg[8 * s + 7] };
            *(bf16x8*)&Wl[wr][wkb + 8 * s] = v;
        }
    };

    loadW(0);
    writeW();
    __syncthreads();                    // Wl[tile 0] ready

    for (int it = 0; it < NC * NMT; ++it) {
        if (it + 1 < NC * NMT) loadW(it + 1);   // L2 prefetch under MFMAs
        f32x4 acc[4][2];
        #pragma unroll
        for (int i = 0; i < 4; ++i)
            #pragma unroll
            for (int j = 0; j < 2; ++j) acc[i][j] = 0.f;
        #pragma unroll
        for (int t = 0; t < 6; ++t) {
            bf16x8 af[4];
            #pragma unroll
            for (int mi = 0; mi < 4; ++mi)
                af[mi] = *(const bf16x8*)&Wl[16 * mi + li][32 * t + 8 * gi];
            #pragma unroll
            for (int mi = 0; mi < 4; ++mi)
                #pragma unroll
                for (int ni = 0; ni < 2; ++ni)
                    acc[mi][ni] = __builtin_amdgcn_mfma_f32_16x16x32_bf16(
                        af[mi], xfrag[t][ni], acc[mi][ni], 0, 0, 0);
        }
        // epilogue for this tile
        {
            const int c = it / NMT, j = it % NMT;
            YT* Yb = Y + ga.yoff[z * NC + c] + (long)(64 * j) * N_PIX;
            #pragma unroll
            for (int mi = 0; mi < 4; ++mi)
                #pragma unroll
                for (int ni = 0; ni < 2; ++ni) {
                    const int n = n0 + 32 * w + 16 * ni + li;
                    #pragma unroll
                    for (int r = 0; r < 4; ++r)
                        Yb[(long)(16 * mi + 4 * gi + r) * N_PIX + n] =
                            (YT)acc[mi][ni][r];
                }
        }
        __syncthreads();                // everyone done reading Wl
        if (it + 1 < NC * NMT) {
            writeW();                   // waits vmcnt for prefetched W
            __syncthreads();            // Wl[next] ready
        }
    }
}

// ---------------- depthwise 3x3 + fused row L2-norm ----------------
__global__ __launch_bounds__(256) void dwconv3b(const bf16_t* __restrict__ Yin,
    const float* __restrict__ wdw, bf16_t* __restrict__ Z,
    float* __restrict__ invn)
{
    const int ch = blockIdx.x, sb = blockIdx.y;
    const int tid = threadIdx.x;
    const int x0 = (tid & 15) << 3;
    const int y0 = (tid >> 4) << 3;
    const bf16_t* __restrict__ inp = Yin + (long)(sb * C3 + ch) * N_PIX;
    bf16_t* __restrict__ outp = Z + (long)(sb * C3 + ch) * N_PIX;
    const float* wch = wdw + ch * 9;
    const float w00 = wch[0], w01 = wch[1], w02 = wch[2];
    const float w10 = wch[3], w11 = wch[4], w12 = wch[5];
    const float w20 = wch[6], w21 = wch[7], w22 = wch[8];
    const bool hasL = (x0 > 0), hasR = (x0 < 120);
    float A[10], B[10], Cr[10];
    auto loadrow = [&](int yy, float* r) {
        if (yy < 0 || yy > 127) {
            #pragma unroll
            for (int i = 0; i < 10; ++i) r[i] = 0.f;
            return;
        }
        const bf16_t* p = inp + (yy << 7);
        bf16x8 v = *(const bf16x8*)(p + x0);
        #pragma unroll
        for (int j = 0; j < 8; ++j) r[1 + j] = (float)v[j];
        r[0] = hasL ? (float)p[x0 - 1] : 0.f;
        r[9] = hasR ? (float)p[x0 + 8] : 0.f;
    };
    loadrow(y0 - 1, A);
    loadrow(y0,     B);
    float ss = 0.f;
    #pragma unroll
    for (int r = 0; r < 8; ++r) {
        loadrow(y0 + r + 1, Cr);
        bf16x8 ov;
        #pragma unroll
        for (int i = 0; i < 8; ++i) {
            float s;
            s = fmaf(w00, A[i],  fmaf(w01, A[i + 1],  w02 * A[i + 2]));
            s = fmaf(w10, B[i],  fmaf(w11, B[i + 1],  fmaf(w12, B[i + 2], s)));
            s = fmaf(w20, Cr[i], fmaf(w21, Cr[i + 1], fmaf(w22, Cr[i + 2], s)));
            ov[i] = (bf16_t)s;
            const float vb = (float)ov[i];
            ss = fmaf(vb, vb, ss);
        }
        *(bf16x8*)(outp + ((y0 + r) << 7) + x0) = ov;
        #pragma unroll
        for (int i = 0; i < 10; ++i) { A[i] = B[i]; B[i] = Cr[i]; }
    }
    if (ch < 384) {
        #pragma unroll
        for (int off = 32; off > 0; off >>= 1) ss += __shfl_down(ss, off);
        __shared__ float red[4];
        if ((tid & 63) == 0) red[tid >> 6] = ss;
        __syncthreads();
        if (tid == 0) {
            const float t = red[0] + red[1] + red[2] + red[3];
            const int row = (sb >> 2) * 1536 + (sb & 3) * 384 + ch;
            invn[row] = 1.f / fmaxf(sqrtf(t), 1e-12f);
        }
    }
}

// ---------------- MFMA score partials: all 4 combos share one LDS stage ------
__global__ __launch_bounds__(256) void scores_mfma(const bf16_t* __restrict__ Z,
                                                   float* __restrict__ part)
{
    const int c = blockIdx.x;
    const int bh = blockIdx.y;
    const int b = bh >> 2, h = bh & 3;
    __shared__ __align__(16) bf16_t T[4][48][72];   // qe, qd, ke, kd
    const int tid = threadIdx.x;
    const int m = tid >> 6;
    const int gi = (tid >> 4) & 3, li = tid & 15;
    const int qs = (m == 1 || m == 3) ? 1 : 0;
    const int ks = (m == 1 || m == 2) ? 1 : 0;
    f32x4 acc[3][3];
    #pragma unroll
    for (int i = 0; i < 3; ++i)
        #pragma unroll
        for (int j = 0; j < 3; ++j) acc[i][j] = 0.f;

    const int nbase = c * CHUNK;
    for (int k0 = 0; k0 < CHUNK; k0 += 64) {
        __syncthreads();
        for (int l = tid; l < 1536; l += 256) {
            const int t = l / 384;
            const int rem = l - t * 384;
            const int r = rem >> 3, s = rem & 7;
            const int sidx = (t < 2) ? t : (t - 2);
            const int qk = (t < 2) ? 0 : 1;
            const bf16_t* gp = Z + ((long)((sidx * 4 + b) * C3 + qk * 192 + h * 48 + r)) * N_PIX
                                 + nbase + k0 + s * 8;
            *(bf16x8*)&T[t][r][s * 8] = *(const bf16x8*)gp;
        }
        __syncthreads();
        #pragma unroll
        for (int k2 = 0; k2 < 64; k2 += 32) {
            bf16x8 af[3], bfr[3];
            #pragma unroll
            for (int i = 0; i < 3; ++i) {
                bf16x4 lo = *(const bf16x4*)&T[qs][16 * i + li][k2 + 4 * gi];
                bf16x4 hi = *(const bf16x4*)&T[qs][16 * i + li][k2 + 16 + 4 * gi];
                af[i] = __builtin_shufflevector(lo, hi, 0, 1, 2, 3, 4, 5, 6, 7);
            }
            #pragma unroll
            for (int j = 0; j < 3; ++j) {
                bf16x4 lo = *(const bf16x4*)&T[2 + ks][16 * j + li][k2 + 4 * gi];
                bf16x4 hi = *(const bf16x4*)&T[2 + ks][16 * j + li][k2 + 16 + 4 * gi];
                bfr[j] = __builtin_shufflevector(lo, hi, 0, 1, 2, 3, 4, 5, 6, 7);
            }
            #pragma unroll
            for (int i = 0; i < 3; ++i)
                #pragma unroll
                for (int j = 0; j < 3; ++j)
                    acc[i][j] = __builtin_amdgcn_mfma_f32_16x16x32_bf16(
                        af[i], bfr[j], acc[i][j], 0, 0, 0);
        }
    }
    const long base = ((long)(m * 16 + bh) * NCH + c) * 2304;
    #pragma unroll
    for (int i = 0; i < 3; ++i)
        #pragma unroll
        for (int j = 0; j < 3; ++j) {
            const int e = 16 * j + li;
            #pragma unroll
            for (int r = 0; r < 4; ++r) {
                const int d = 16 * i + 4 * gi + r;
                part[base + d * 48 + e] = acc[i][j][r];
            }
        }
}

// ---------------- reduce partials, scale by norms+temperature, softmax -------
__global__ __launch_bounds__(256) void reduce_softmax(const float* __restrict__ part,
    const float* __restrict__ invn, const float* __restrict__ temp,
    float* __restrict__ attn)
{
    const int mbh = blockIdx.x;                 // 64
    const int m = mbh >> 4, b = (mbh >> 2) & 3, h = mbh & 3;
    const int qs = (m == 1 || m == 3) ? 1 : 0;
    const int ks = (m == 1 || m == 2) ? 1 : 0;
    __shared__ float sm[48][48];
    const int tid = threadIdx.x;
    const long pbase = (long)mbh * NCH * 2304;
    const float T = temp[h];
    for (int idx = tid; idx < 2304; idx += 256) {
        float v = 0.f;
        #pragma unroll 8
        for (int c = 0; c < NCH; ++c) v += part[pbase + c * 2304 + idx];
        const int d = idx / 48, e = idx % 48;
        const float iq = invn[(qs * 4 + b) * 384 + h * 48 + d];
        const float ik = invn[(ks * 4 + b) * 384 + 192 + h * 48 + e];
        sm[d][e] = v * iq * ik * T;
    }
    __syncthreads();
    if (tid < 48) {
        float mx = -1e30f;
        #pragma unroll
        for (int e = 0; e < 48; ++e) mx = fmaxf(mx, sm[tid][e]);
        float sum = 0.f;
        #pragma unroll
        for (int e = 0; e < 48; ++e) {
            const float v = __expf(sm[tid][e] - mx);
            sm[tid][e] = v;
            sum += v;
        }
        const float inv = 1.f / sum;
        const long abase = (long)mbh * 2304 + (long)tid * 48;
        #pragma unroll
        for (int e = 0; e < 48; ++e) attn[abase + e] = sm[tid][e] * inv;
    }
}

// ---------------- fold attn into projection: M[m][b][o][h*48+e] --------------
// m==3 (inter_de): einsum '...de,bhen->bhdn' SUMS the ellipsis dims.
__global__ __launch_bounds__(256) void make_M(const float* __restrict__ attn,
                                              WPtrs wp, float* __restrict__ M)
{
    const int h = blockIdx.x & 3;
    const int b = (blockIdx.x >> 2) & 3;
    const int m = blockIdx.x >> 4;              // grid 64
    __shared__ float A[48][48];
    const int tid = threadIdx.x;
    if (m == 3) {
        for (int l = tid; l < 2304; l += 256) {
            float s = 0.f;
            #pragma unroll
            for (int bb = 0; bb < 16; ++bb)
                s += attn[(long)(48 + bb) * 2304 + l];
            A[l / 48][l % 48] = s;
        }
    } else {
        const long ab = (long)(m * 16 + b * 4 + h) * 2304;
        for (int l = tid; l < 2304; l += 256)
            A[l / 48][l % 48] = attn[ab + l];
    }
    __syncthreads();
    const float* W = wp.p[m];
    float* Mo = M + (long)(m * 4 + b) * 192 * 192;
    for (int o = tid >> 4; o < 192; o += 16) {
        const float* wrow = W + (long)o * 192 + h * 48;
        for (int e2 = tid & 15; e2 < 48; e2 += 16) {
            float s = 0.f;
            #pragma unroll
            for (int d = 0; d < 48; ++d) s = fmaf(wrow[d], A[d][e2], s);
            Mo[(long)o * 192 + h * 48 + e2] = s;
        }
    }
}

extern "C" void kernel_launch(void* const* d_in, const int* in_sizes, int n_in,
                              void* d_out, int out_size, void* d_ws, size_t ws_size,
                              hipStream_t stream)
{
    const float* e     = (const float*)d_in[0];
    const float* d     = (const float*)d_in[1];
    const float* temp  = (const float*)d_in[2];
    const float* w_qkv = (const float*)d_in[3];
    const float* w_dw  = (const float*)d_in[4];
    const float* w_p1  = (const float*)d_in[5];
    const float* w_p2  = (const float*)d_in[6];
    const float* w_p3  = (const float*)d_in[7];
    const float* w_p4  = (const float*)d_in[8];
    float* out = (float*)d_out;
    float* ws  = (float*)d_ws;

    // workspace layout (float units)
    bf16_t* zraw = (bf16_t*)ws;                // 75,497,472 bf16 (qkv raw)
    bf16_t* zb   = (bf16_t*)(ws + 37748736L);  // 75,497,472 bf16
    float* attn  = ws + 75497472L;             // 147,456
    float* invn  = ws + 75644928L;             // 3,072
    // part & M reuse the zraw region once it's dead (after dwconv3b)
    float* part  = ws;                         // 4,718,592 f32
    float* Mmat  = ws + 8388608L;              // 589,824 f32

    const long sXin = (long)CC * N_PIX;
    const long sQKV = (long)C3 * N_PIX;

    // 1) pointwise qkv GEMM, bf16 out — z = (s,b) panel; 9 m-tiles per block
    GArgs gq{};
    for (int z = 0; z < 8; ++z) {
        gq.W[z] = w_qkv;
        gq.xoff[z] = (long)(z & 3) * sXin;
        gq.yoff[z] = (long)z * sQKV;
        gq.sel[z] = z >> 2;
    }
    gemm_mloop<float, bf16_t, 1, 9><<<dim3(128, 8), 256, 0, stream>>>(gq, e, d, zraw);
    // 2) depthwise 3x3 (bf16 -> bf16) + fused q/k row norms
    dwconv3b<<<dim3(C3, 8), 256, 0, stream>>>(zraw, w_dw, zb, invn);
    // 3) MFMA score partials, 4 combos fused
    scores_mfma<<<dim3(NCH, 16), 256, 0, stream>>>(zb, part);
    // 4) reduce + scale + softmax
    reduce_softmax<<<dim3(64), 256, 0, stream>>>(part, invn, temp, attn);
    // 5) fold attn into projection matrices
    WPtrs wpj; wpj.p[0] = w_p1; wpj.p[1] = w_p2; wpj.p[2] = w_p3; wpj.p[3] = w_p4;
    make_M<<<dim3(64), 256, 0, stream>>>(attn, wpj, Mmat);
    // 6) fused (proj ∘ attn) @ V: z = V panel (s,b); 2 combos x 3 m-tiles per
    //    block, V read ONCE. s=0 panels serve m in {0,3}; s=1 serve {1,2}.
    GArgs gm{};
    for (int z = 0; z < 8; ++z) {
        const int s = z >> 2, b = z & 3;
        gm.xoff[z] = ((long)((s * 4 + b) * C3 + 384)) * N_PIX;
        gm.sel[z] = 0;
        for (int c = 0; c < 2; ++c) {
            const int midx = (s == 0) ? (c ? 3 : 0) : (c ? 2 : 1);
            gm.W[2 * z + c] = Mmat + (long)(midx * 4 + b) * 192 * 192;
            gm.yoff[2 * z + c] = (long)(midx * 4 + b) * sXin;
        }
    }
    gemm_mloop<bf16_t, float, 2, 3><<<dim3(128, 8), 256, 0, stream>>>(gm, zb, zb, out);
}